// Round 5
// baseline (566.388 us; speedup 1.0000x reference)
//
#include <hip/hip_runtime.h>
#include <hip/hip_fp16.h>

// NNUE forward: embedding-bag (2x32 gathers of 256-dim rows) -> clipped relu
// -> 512->32->32->1 MLP. One wave per batch element.
//
// R5 = R4 with compile fixes (ROCm 7.2 fp16 header has no gfx950 __hmax2/
// __hmin2 overloads -> use native ext-vector '+' for v_pk_add_f16 and inline
// asm v_pk_max/min_f16 for the packed clip).
//  - gather accumulates in packed f16 (v_pk_add_f16, 2 interleaved sets)
//  - layer1/layer2 dot products via v_dot2_f32_f16 (f32 accumulate)
//  - x stays packed f16 end-to-end
//  - 512-thread blocks (8 waves share the 33KB LDS) -> higher occupancy

constexpr int kBatch  = 131072;
constexpr int kHidden = 256;
constexpr int kBag    = 32;
constexpr int kFeat   = 40960;

__device__ __forceinline__ float clip1(float x) {
  return fminf(fmaxf(x, 0.0f), 1.0f);  // v_med3_f32
}

typedef _Float16 h2_t __attribute__((ext_vector_type(2)));

__device__ __forceinline__ unsigned pkadd(unsigned a, unsigned b) {
  const h2_t r = __builtin_bit_cast(h2_t, a) + __builtin_bit_cast(h2_t, b);
  return __builtin_bit_cast(unsigned, r);  // v_pk_add_f16
}

__device__ __forceinline__ unsigned pkclip(unsigned a) {
  unsigned r;
  const unsigned zero = 0u;            // {0.0h, 0.0h}
  const unsigned one  = 0x3C003C00u;   // {1.0h, 1.0h}
  asm("v_pk_max_f16 %0, %1, %2\n\t"
      "v_pk_min_f16 %0, %0, %3"
      : "=&v"(r)
      : "v"(a), "v"(zero), "v"(one));
  return r;
}

// v_dot2_f32_f16: c += a.x*b.x + a.y*b.y (f32 accumulate, f16 inputs)
__device__ __forceinline__ float fdot2w(unsigned a, unsigned b, float c) {
  return __builtin_amdgcn_fdot2(__builtin_bit_cast(h2_t, a),
                                __builtin_bit_cast(h2_t, b), c, false);
}

// One butterfly reduce-scatter stage; ALL indices compile-time constants so
// p[] stays in VGPRs (rule #20: no runtime indexing).
template <int D, int HALF>
__device__ __forceinline__ void rs_stage(float (&p)[32], int lane) {
  const bool up = (lane & D) != 0;
#pragma unroll
  for (int i = 0; i < HALF; ++i) {
    const float send = up ? p[i] : p[i + HALF];
    const float recv = __shfl_xor(send, D, 64);
    p[i] = (up ? p[i + HALF] : p[i]) + recv;
  }
}

// Full 64-lane reduce of 32 per-lane partials; sum of p[j] over all lanes
// delivered to lanes 2j and 2j+1 (j = lane>>1).
__device__ __forceinline__ float reduce32(float (&p)[32], int lane) {
  rs_stage<32, 16>(p, lane);
  rs_stage<16, 8>(p, lane);
  rs_stage<8, 4>(p, lane);
  rs_stage<4, 2>(p, lane);
  rs_stage<2, 1>(p, lane);
  return p[0] + __shfl_xor(p[0], 1, 64);
}

// ---------------------------------------------------------------------------
// emb f32 -> f16 (RNE) convert, 8B coalesced stores
__global__ void cvt_emb(const float4* __restrict__ src, uint2* __restrict__ dst) {
  const int n4 = kFeat * kHidden / 4;
  const int stride = gridDim.x * blockDim.x;
  for (int i = blockIdx.x * blockDim.x + threadIdx.x; i < n4; i += stride) {
    const float4 v = src[i];
    union { __half2 h[2]; uint2 u; } P;
    P.h[0] = __floats2half2_rn(v.x, v.y);
    P.h[1] = __floats2half2_rn(v.z, v.w);
    dst[i] = P.u;
  }
}

// ---------------------------------------------------------------------------
// f16 fast path: 512-thread blocks, 8 waves share 33KB LDS
constexpr int kBlocksH = 1024;
constexpr int kTpb     = 512;
constexpr int kWpb     = kTpb / 64;                     // 8
constexpr int kElemsH  = kBatch / (kBlocksH * kWpb);    // 16
static_assert(kBatch % (kBlocksH * kWpb) == 0);

__global__ __launch_bounds__(kTpb, 6) void nnue_fwd_h(
    const int* __restrict__ idx_us, const int* __restrict__ idx_th,
    const __half* __restrict__ embh, const float* __restrict__ w1,
    const float* __restrict__ b1, const float* __restrict__ w2,
    const float* __restrict__ b2, const float* __restrict__ wo,
    const float* __restrict__ bo, float* __restrict__ out) {
  // sW1h linear layout == row-major f16 W1: entry (j, L, k) = w1[j][8L+k].
  __shared__ __align__(16) __half sW1h[32 * 512];          // 32 KB
  __shared__ __align__(16) __half sY1h[kWpb][32];          // per-wave y1 (f16)

  const int t = threadIdx.x;
  {  // stage W1 as f16: thread t converts floats [32t, 32t+32)
    const float4* src = (const float4*)w1;
#pragma unroll
    for (int c = 0; c < 8; ++c) {
      const float4 v = src[t * 8 + c];
      __half2* d = (__half2*)&sW1h[t * 32 + 4 * c];
      d[0] = __floats2half2_rn(v.x, v.y);
      d[1] = __floats2half2_rn(v.z, v.w);
    }
  }
  __syncthreads();

  const int lane    = t & 63;
  const int wlocal  = t >> 6;
  const int wid     = blockIdx.x * kWpb + wlocal;
  const int myj     = lane >> 1;   // layer-1 output this lane ends up holding
  const int j2      = lane & 31;   // layer-2/3 row this lane owns
  const int half31  = lane & 31;
  const bool hiHalf = lane >= 32;

  // Small weights pinned in registers.
  const float b1r  = b1[myj];
  const float b2r  = b2[j2];
  const float wor  = wo[j2];
  const float outb = bo[0];
  unsigned w2h[16];  // lane's W2 row, packed f16; constant-indexed only
#pragma unroll
  for (int k = 0; k < 16; ++k) {
    w2h[k] = __builtin_bit_cast(
        unsigned, __floats2half2_rn(w2[j2 * 32 + 2 * k], w2[j2 * 32 + 2 * k + 1]));
  }

  for (int e = 0; e < kElemsH; ++e) {
    const int b = wid * kElemsH + e;

    // lanes 0..31 hold us-indices, lanes 32..63 hold them-indices
    const int* ip = (lane < kBag) ? (idx_us + (size_t)b * kBag + lane)
                                  : (idx_th + (size_t)b * kBag + (lane - kBag));
    const int vidx = *ip;

    // ---- gather: each 1KB load covers TWO f16 rows (half-wave each). ----
    // Packed f16 accumulate, 2 interleaved sets (ILP + halved rounding depth)
    unsigned aU[8] = {0, 0, 0, 0, 0, 0, 0, 0};
    unsigned aT[8] = {0, 0, 0, 0, 0, 0, 0, 0};
#pragma unroll
    for (int s = 0; s < 16; ++s) {
      const int rA = __builtin_amdgcn_readlane(vidx, 2 * s);
      const int rB = __builtin_amdgcn_readlane(vidx, 2 * s + 1);
      const int row = hiHalf ? rB : rA;
      const uint4 v = ((const uint4*)embh)[row * 32 + half31];
      const int o = (s & 1) * 4;
      aU[o + 0] = pkadd(aU[o + 0], v.x);
      aU[o + 1] = pkadd(aU[o + 1], v.y);
      aU[o + 2] = pkadd(aU[o + 2], v.z);
      aU[o + 3] = pkadd(aU[o + 3], v.w);
    }
#pragma unroll
    for (int s = 0; s < 16; ++s) {
      const int rA = __builtin_amdgcn_readlane(vidx, 32 + 2 * s);
      const int rB = __builtin_amdgcn_readlane(vidx, 33 + 2 * s);
      const int row = hiHalf ? rB : rA;
      const uint4 v = ((const uint4*)embh)[row * 32 + half31];
      const int o = (s & 1) * 4;
      aT[o + 0] = pkadd(aT[o + 0], v.x);
      aT[o + 1] = pkadd(aT[o + 1], v.y);
      aT[o + 2] = pkadd(aT[o + 2], v.z);
      aT[o + 3] = pkadd(aT[o + 3], v.w);
    }

    // merge sets + fold half-wave partials + clip; x stays packed f16.
    unsigned x2[4];
#pragma unroll
    for (int q = 0; q < 4; ++q) {
      unsigned u = pkadd(aU[q], aU[q + 4]);
      unsigned v = pkadd(aT[q], aT[q + 4]);
      u = pkadd(u, (unsigned)__shfl_xor((int)u, 32, 64));
      v = pkadd(v, (unsigned)__shfl_xor((int)v, 32, 64));
      x2[q] = pkclip(hiHalf ? v : u);
    }

    // ---- layer 1: p[j] = dot(w1[j][8*lane..+8), x2) via v_dot2 ----
    float p[32];
#pragma unroll
    for (int j = 0; j < 32; ++j) {
      const uint4 wv = *(const uint4*)&sW1h[(j * 64 + lane) * 8];
      float s = fdot2w(wv.x, x2[0], 0.0f);
      s = fdot2w(wv.y, x2[1], s);
      s = fdot2w(wv.z, x2[2], s);
      s = fdot2w(wv.w, x2[3], s);
      p[j] = s;
    }
    const float y1 = clip1(reduce32(p, lane) + b1r);  // lanes 2j,2j+1 hold y1[j]

    // publish y1[0..31] to the wave via per-wave LDS (same-wave, no barrier)
    if ((lane & 1) == 0) sY1h[wlocal][myj] = __float2half(y1);
    asm volatile("s_waitcnt lgkmcnt(0)" ::: "memory");

    // ---- layer 2: y2[j2] = dot(w2[j2][:], y1[:]) via v_dot2 ----
    const uint4* yv = (const uint4*)&sY1h[wlocal][0];  // 64B, broadcast reads
    float y2 = b2r;
#pragma unroll
    for (int k4 = 0; k4 < 4; ++k4) {
      const uint4 y = yv[k4];
      y2 = fdot2w(w2h[4 * k4 + 0], y.x, y2);
      y2 = fdot2w(w2h[4 * k4 + 1], y.y, y2);
      y2 = fdot2w(w2h[4 * k4 + 2], y.z, y2);
      y2 = fdot2w(w2h[4 * k4 + 3], y.w, y2);
    }
    y2 = clip1(y2);

    // ---- output layer: sum over j2 within each 32-lane half ----
    float acc = y2 * wor;
#pragma unroll
    for (int d = 1; d < 32; d <<= 1) acc += __shfl_xor(acc, d, 64);
    if (lane == 0) out[b] = acc + outb;
  }
}

// ---------------------------------------------------------------------------
// f32 fallback in case ws_size can't hold the f16 table
constexpr int kTpbF    = 256;
constexpr int kWpbF    = kTpbF / 64;
constexpr int kBlocksF = 512;
constexpr int kElemsF  = kBatch / (kBlocksF * kWpbF);  // 64

__global__ __launch_bounds__(kTpbF, 2) void nnue_fwd_f32(
    const int* __restrict__ idx_us, const int* __restrict__ idx_th,
    const float* __restrict__ emb, const float* __restrict__ w1,
    const float* __restrict__ b1, const float* __restrict__ w2,
    const float* __restrict__ b2, const float* __restrict__ wo,
    const float* __restrict__ bo, float* __restrict__ out) {
  __shared__ float sW1[32][512];
  __shared__ __align__(16) float sY1[kWpbF][32];

  const int t = threadIdx.x;
  {
    const float4* src = (const float4*)w1;
    float4* dst = (float4*)&sW1[0][0];
#pragma unroll
    for (int i = 0; i < 16; ++i) dst[i * kTpbF + t] = src[i * kTpbF + t];
  }
  __syncthreads();

  const int lane   = t & 63;
  const int wlocal = t >> 6;
  const int wid    = blockIdx.x * kWpbF + wlocal;
  const int myj    = lane >> 1;
  const int j2     = lane & 31;

  const float b1r  = b1[myj];
  const float b2r  = b2[j2];
  const float wor  = wo[j2];
  const float outb = bo[0];
  float w2r[32];
#pragma unroll
  for (int k = 0; k < 32; ++k) w2r[k] = w2[j2 * 32 + k];

  for (int e = 0; e < kElemsF; ++e) {
    const int b = wid * kElemsF + e;
    const int* ip = (lane < kBag) ? (idx_us + (size_t)b * kBag + lane)
                                  : (idx_th + (size_t)b * kBag + (lane - kBag));
    const int vidx = *ip;

    float4 au = make_float4(0.f, 0.f, 0.f, 0.f);
    float4 at = make_float4(0.f, 0.f, 0.f, 0.f);
#pragma unroll
    for (int i = 0; i < kBag; ++i) {
      const int iu = __builtin_amdgcn_readlane(vidx, i);
      const float4 v = ((const float4*)(emb + (size_t)iu * kHidden))[lane];
      au.x += v.x; au.y += v.y; au.z += v.z; au.w += v.w;
    }
#pragma unroll
    for (int i = 0; i < kBag; ++i) {
      const int it2 = __builtin_amdgcn_readlane(vidx, i + kBag);
      const float4 v = ((const float4*)(emb + (size_t)it2 * kHidden))[lane];
      at.x += v.x; at.y += v.y; at.z += v.z; at.w += v.w;
    }

    au.x = clip1(au.x); au.y = clip1(au.y); au.z = clip1(au.z); au.w = clip1(au.w);
    at.x = clip1(at.x); at.y = clip1(at.y); at.z = clip1(at.z); at.w = clip1(at.w);

    float p[32];
#pragma unroll
    for (int j = 0; j < 32; ++j) {
      const float4 a = *(const float4*)&sW1[j][4 * lane];
      const float4 c = *(const float4*)&sW1[j][kHidden + 4 * lane];
      p[j] = au.x * a.x + au.y * a.y + au.z * a.z + au.w * a.w +
             at.x * c.x + at.y * c.y + at.z * c.z + at.w * c.w;
    }
    const float y1 = clip1(reduce32(p, lane) + b1r);

    if ((lane & 1) == 0) sY1[wlocal][myj] = y1;
    asm volatile("s_waitcnt lgkmcnt(0)" ::: "memory");

    const float4* y4 = (const float4*)&sY1[wlocal][0];
    float y2 = b2r;
#pragma unroll
    for (int k4 = 0; k4 < 8; ++k4) {
      const float4 y = y4[k4];
      y2 += w2r[4 * k4 + 0] * y.x + w2r[4 * k4 + 1] * y.y +
            w2r[4 * k4 + 2] * y.z + w2r[4 * k4 + 3] * y.w;
    }
    y2 = clip1(y2);

    float acc = y2 * wor;
#pragma unroll
    for (int d = 1; d < 32; d <<= 1) acc += __shfl_xor(acc, d, 64);
    if (lane == 0) out[b] = acc + outb;
  }
}

extern "C" void kernel_launch(void* const* d_in, const int* in_sizes, int n_in,
                              void* d_out, int out_size, void* d_ws, size_t ws_size,
                              hipStream_t stream) {
  const int* idx_us  = (const int*)d_in[0];
  const int* idx_th  = (const int*)d_in[1];
  const float* emb   = (const float*)d_in[2];
  const float* w1    = (const float*)d_in[3];
  const float* b1    = (const float*)d_in[4];
  const float* w2    = (const float*)d_in[5];
  const float* b2    = (const float*)d_in[6];
  const float* wo    = (const float*)d_in[7];
  const float* bo    = (const float*)d_in[8];
  float* out         = (float*)d_out;

  const size_t embh_bytes = (size_t)kFeat * kHidden * sizeof(__half);  // 21 MB
  if (ws_size >= embh_bytes) {
    __half* embh = (__half*)d_ws;
    cvt_emb<<<2048, 256, 0, stream>>>((const float4*)emb, (uint2*)embh);
    nnue_fwd_h<<<kBlocksH, kTpb, 0, stream>>>(idx_us, idx_th, embh, w1, b1, w2,
                                              b2, wo, bo, out);
  } else {
    nnue_fwd_f32<<<kBlocksF, kTpbF, 0, stream>>>(idx_us, idx_th, emb, w1, b1,
                                                 w2, b2, wo, bo, out);
  }
}

// Round 6
// 488.563 us; speedup vs baseline: 1.1593x; 1.1593x over previous
//
#include <hip/hip_runtime.h>
#include <hip/hip_fp16.h>

// NNUE forward: embedding-bag (2x32 gathers of 256-dim rows) -> clipped relu
// -> 512->32->32->1 MLP.
//
// R6: memory-level-parallelism round. R5 showed VALUBusy 28%, occ 54%, FETCH
// unchanged, yet SLOWER than R3 with its 40-VGPR/2-inflight-load waves ->
// gather is latency/MLP-bound, not purely fabric-BW-bound. Changes:
//  - TWO elements per wave with interleaved gather streams (2 independent
//    load chains -> ~2x outstanding bytes per wave)
//  - 256-thr blocks, __launch_bounds__(256,4): VGPR cap 128, 4 blocks/CU
//    (33 KB LDS each) = 16 waves/CU
//  - keeps R5's packed-f16 accumulate + v_dot2_f32_f16 MLP

constexpr int kBatch  = 131072;
constexpr int kHidden = 256;
constexpr int kBag    = 32;
constexpr int kFeat   = 40960;

__device__ __forceinline__ float clip1(float x) {
  return fminf(fmaxf(x, 0.0f), 1.0f);  // v_med3_f32
}

typedef _Float16 h2_t __attribute__((ext_vector_type(2)));

__device__ __forceinline__ unsigned pkadd(unsigned a, unsigned b) {
  const h2_t r = __builtin_bit_cast(h2_t, a) + __builtin_bit_cast(h2_t, b);
  return __builtin_bit_cast(unsigned, r);  // v_pk_add_f16
}

__device__ __forceinline__ unsigned pkclip(unsigned a) {
  unsigned r;
  const unsigned zero = 0u;            // {0.0h, 0.0h}
  const unsigned one  = 0x3C003C00u;   // {1.0h, 1.0h}
  asm("v_pk_max_f16 %0, %1, %2\n\t"
      "v_pk_min_f16 %0, %0, %3"
      : "=&v"(r)
      : "v"(a), "v"(zero), "v"(one));
  return r;
}

// v_dot2_f32_f16: c += a.x*b.x + a.y*b.y (f32 accumulate, f16 inputs)
__device__ __forceinline__ float fdot2w(unsigned a, unsigned b, float c) {
  return __builtin_amdgcn_fdot2(__builtin_bit_cast(h2_t, a),
                                __builtin_bit_cast(h2_t, b), c, false);
}

// One butterfly reduce-scatter stage; ALL indices compile-time constants so
// p[] stays in VGPRs (rule #20: no runtime indexing).
template <int D, int HALF>
__device__ __forceinline__ void rs_stage(float (&p)[32], int lane) {
  const bool up = (lane & D) != 0;
#pragma unroll
  for (int i = 0; i < HALF; ++i) {
    const float send = up ? p[i] : p[i + HALF];
    const float recv = __shfl_xor(send, D, 64);
    p[i] = (up ? p[i + HALF] : p[i]) + recv;
  }
}

// Full 64-lane reduce of 32 per-lane partials; sum of p[j] over all lanes
// delivered to lanes 2j and 2j+1 (j = lane>>1).
__device__ __forceinline__ float reduce32(float (&p)[32], int lane) {
  rs_stage<32, 16>(p, lane);
  rs_stage<16, 8>(p, lane);
  rs_stage<8, 4>(p, lane);
  rs_stage<4, 2>(p, lane);
  rs_stage<2, 1>(p, lane);
  return p[0] + __shfl_xor(p[0], 1, 64);
}

// ---------------------------------------------------------------------------
// emb f32 -> f16 (RNE) convert, 8B coalesced stores
__global__ void cvt_emb(const float4* __restrict__ src, uint2* __restrict__ dst) {
  const int n4 = kFeat * kHidden / 4;
  const int stride = gridDim.x * blockDim.x;
  for (int i = blockIdx.x * blockDim.x + threadIdx.x; i < n4; i += stride) {
    const float4 v = src[i];
    union { __half2 h[2]; uint2 u; } P;
    P.h[0] = __floats2half2_rn(v.x, v.y);
    P.h[1] = __floats2half2_rn(v.z, v.w);
    dst[i] = P.u;
  }
}

// ---------------------------------------------------------------------------
// f16 fast path: 256-thr blocks, 4 blocks/CU, 2 elements per wave-iteration
constexpr int kBlocksH = 1024;
constexpr int kTpb     = 256;
constexpr int kWpb     = kTpb / 64;                       // 4
constexpr int kElemsH  = kBatch / (kBlocksH * kWpb);      // 32 per wave
constexpr int kPairs   = kElemsH / 2;                     // 16 pair-iterations
static_assert(kBatch % (kBlocksH * kWpb) == 0);

// Layers 1-3 for one element given its packed-f16 x (4 regs: this lane's 8
// concat-dims). Inlined; all array indexing compile-time constant.
__device__ __forceinline__ void mlp_tail(
    const __half* __restrict__ sW1h, __half* __restrict__ sy1row,
    const unsigned (&x2)[4], const unsigned (&w2h)[16],
    float b1r, float b2r, float wor, float outb,
    int lane, int myj, float* __restrict__ out, int b) {
  float p[32];
#pragma unroll
  for (int j = 0; j < 32; ++j) {
    const uint4 wv = *(const uint4*)&sW1h[(j * 64 + lane) * 8];
    float s = fdot2w(wv.x, x2[0], 0.0f);
    s = fdot2w(wv.y, x2[1], s);
    s = fdot2w(wv.z, x2[2], s);
    s = fdot2w(wv.w, x2[3], s);
    p[j] = s;
  }
  const float y1 = clip1(reduce32(p, lane) + b1r);  // lanes 2j,2j+1 hold y1[j]

  // publish y1[0..31] to the wave via per-wave LDS (same-wave, in-order DS)
  if ((lane & 1) == 0) sy1row[myj] = __float2half(y1);
  asm volatile("s_waitcnt lgkmcnt(0)" ::: "memory");

  const uint4* yv = (const uint4*)sy1row;  // 64B, broadcast reads
  float y2 = b2r;
#pragma unroll
  for (int k4 = 0; k4 < 4; ++k4) {
    const uint4 y = yv[k4];
    y2 = fdot2w(w2h[4 * k4 + 0], y.x, y2);
    y2 = fdot2w(w2h[4 * k4 + 1], y.y, y2);
    y2 = fdot2w(w2h[4 * k4 + 2], y.z, y2);
    y2 = fdot2w(w2h[4 * k4 + 3], y.w, y2);
  }
  y2 = clip1(y2);

  float acc = y2 * wor;
#pragma unroll
  for (int d = 1; d < 32; d <<= 1) acc += __shfl_xor(acc, d, 64);
  if (lane == 0) out[b] = acc + outb;
}

__global__ __launch_bounds__(kTpb, 4) void nnue_fwd_h(
    const int* __restrict__ idx_us, const int* __restrict__ idx_th,
    const __half* __restrict__ embh, const float* __restrict__ w1,
    const float* __restrict__ b1, const float* __restrict__ w2,
    const float* __restrict__ b2, const float* __restrict__ wo,
    const float* __restrict__ bo, float* __restrict__ out) {
  // sW1h linear layout == row-major f16 W1: entry (j, L, k) = w1[j][8L+k].
  __shared__ __align__(16) __half sW1h[32 * 512];          // 32 KB
  __shared__ __align__(16) __half sY1h[kWpb][32];          // per-wave y1 (f16)

  const int t = threadIdx.x;
  {  // stage W1 as f16: thread t converts floats [64t, 64t+64)
    const float4* src = (const float4*)w1;
#pragma unroll
    for (int c = 0; c < 16; ++c) {
      const float4 v = src[t * 16 + c];
      __half2* d = (__half2*)&sW1h[t * 64 + 4 * c];
      d[0] = __floats2half2_rn(v.x, v.y);
      d[1] = __floats2half2_rn(v.z, v.w);
    }
  }
  __syncthreads();

  const int lane    = t & 63;
  const int wlocal  = t >> 6;
  const int wid     = blockIdx.x * kWpb + wlocal;
  const int myj     = lane >> 1;   // layer-1 output this lane ends up holding
  const int j2      = lane & 31;   // layer-2/3 row this lane owns
  const int half31  = lane & 31;
  const bool hiHalf = lane >= 32;
  const uint4* embq = (const uint4*)embh;

  // Small weights pinned in registers.
  const float b1r  = b1[myj];
  const float b2r  = b2[j2];
  const float wor  = wo[j2];
  const float outb = bo[0];
  unsigned w2h[16];  // lane's W2 row, packed f16; constant-indexed only
#pragma unroll
  for (int k = 0; k < 16; ++k) {
    w2h[k] = __builtin_bit_cast(
        unsigned, __floats2half2_rn(w2[j2 * 32 + 2 * k], w2[j2 * 32 + 2 * k + 1]));
  }

  for (int e = 0; e < kPairs; ++e) {
    const int b0 = wid * kElemsH + 2 * e;
    const int b1i = b0 + 1;

    // lanes 0..31 hold us-indices, lanes 32..63 hold them-indices
    const int* ip0 = (lane < kBag) ? (idx_us + (size_t)b0 * kBag + lane)
                                   : (idx_th + (size_t)b0 * kBag + (lane - kBag));
    const int* ip1 = (lane < kBag) ? (idx_us + (size_t)b1i * kBag + lane)
                                    : (idx_th + (size_t)b1i * kBag + (lane - kBag));
    const int vidx0 = *ip0;
    const int vidx1 = *ip1;

    // ---- gather: two interleaved element streams; each 1KB load covers ----
    // ---- TWO f16 rows (half-wave each); packed f16 acc, 2 sets/stream ----
    unsigned A0[8] = {0, 0, 0, 0, 0, 0, 0, 0};  // e0 "us"
    unsigned T0[8] = {0, 0, 0, 0, 0, 0, 0, 0};  // e0 "them"
    unsigned A1[8] = {0, 0, 0, 0, 0, 0, 0, 0};  // e1 "us"
    unsigned T1[8] = {0, 0, 0, 0, 0, 0, 0, 0};  // e1 "them"
#pragma unroll
    for (int s = 0; s < 16; ++s) {
      const int r0A = __builtin_amdgcn_readlane(vidx0, 2 * s);
      const int r0B = __builtin_amdgcn_readlane(vidx0, 2 * s + 1);
      const int r1A = __builtin_amdgcn_readlane(vidx1, 2 * s);
      const int r1B = __builtin_amdgcn_readlane(vidx1, 2 * s + 1);
      const uint4 v0 = embq[(size_t)(hiHalf ? r0B : r0A) * 32 + half31];
      const uint4 v1 = embq[(size_t)(hiHalf ? r1B : r1A) * 32 + half31];
      const int o = (s & 1) * 4;
      A0[o + 0] = pkadd(A0[o + 0], v0.x);
      A0[o + 1] = pkadd(A0[o + 1], v0.y);
      A0[o + 2] = pkadd(A0[o + 2], v0.z);
      A0[o + 3] = pkadd(A0[o + 3], v0.w);
      A1[o + 0] = pkadd(A1[o + 0], v1.x);
      A1[o + 1] = pkadd(A1[o + 1], v1.y);
      A1[o + 2] = pkadd(A1[o + 2], v1.z);
      A1[o + 3] = pkadd(A1[o + 3], v1.w);
    }
#pragma unroll
    for (int s = 0; s < 16; ++s) {
      const int r0A = __builtin_amdgcn_readlane(vidx0, 32 + 2 * s);
      const int r0B = __builtin_amdgcn_readlane(vidx0, 33 + 2 * s);
      const int r1A = __builtin_amdgcn_readlane(vidx1, 32 + 2 * s);
      const int r1B = __builtin_amdgcn_readlane(vidx1, 33 + 2 * s);
      const uint4 v0 = embq[(size_t)(hiHalf ? r0B : r0A) * 32 + half31];
      const uint4 v1 = embq[(size_t)(hiHalf ? r1B : r1A) * 32 + half31];
      const int o = (s & 1) * 4;
      T0[o + 0] = pkadd(T0[o + 0], v0.x);
      T0[o + 1] = pkadd(T0[o + 1], v0.y);
      T0[o + 2] = pkadd(T0[o + 2], v0.z);
      T0[o + 3] = pkadd(T0[o + 3], v0.w);
      T1[o + 0] = pkadd(T1[o + 0], v1.x);
      T1[o + 1] = pkadd(T1[o + 1], v1.y);
      T1[o + 2] = pkadd(T1[o + 2], v1.z);
      T1[o + 3] = pkadd(T1[o + 3], v1.w);
    }

    // merge sets + fold half-wave partials + clip; x stays packed f16.
    unsigned x20[4], x21[4];
#pragma unroll
    for (int q = 0; q < 4; ++q) {
      unsigned u0 = pkadd(A0[q], A0[q + 4]);
      unsigned t0 = pkadd(T0[q], T0[q + 4]);
      unsigned u1 = pkadd(A1[q], A1[q + 4]);
      unsigned t1 = pkadd(T1[q], T1[q + 4]);
      u0 = pkadd(u0, (unsigned)__shfl_xor((int)u0, 32, 64));
      t0 = pkadd(t0, (unsigned)__shfl_xor((int)t0, 32, 64));
      u1 = pkadd(u1, (unsigned)__shfl_xor((int)u1, 32, 64));
      t1 = pkadd(t1, (unsigned)__shfl_xor((int)t1, 32, 64));
      x20[q] = pkclip(hiHalf ? t0 : u0);
      x21[q] = pkclip(hiHalf ? t1 : u1);
    }

    // ---- MLP for both elements (serial; VALU is cheap here) ----
    mlp_tail(sW1h, &sY1h[wlocal][0], x20, w2h, b1r, b2r, wor, outb, lane, myj,
             out, b0);
    mlp_tail(sW1h, &sY1h[wlocal][0], x21, w2h, b1r, b2r, wor, outb, lane, myj,
             out, b1i);
  }
}

// ---------------------------------------------------------------------------
// f32 fallback in case ws_size can't hold the f16 table
constexpr int kTpbF    = 256;
constexpr int kWpbF    = kTpbF / 64;
constexpr int kBlocksF = 512;
constexpr int kElemsF  = kBatch / (kBlocksF * kWpbF);  // 64

__global__ __launch_bounds__(kTpbF, 2) void nnue_fwd_f32(
    const int* __restrict__ idx_us, const int* __restrict__ idx_th,
    const float* __restrict__ emb, const float* __restrict__ w1,
    const float* __restrict__ b1, const float* __restrict__ w2,
    const float* __restrict__ b2, const float* __restrict__ wo,
    const float* __restrict__ bo, float* __restrict__ out) {
  __shared__ float sW1[32][512];
  __shared__ __align__(16) float sY1[kWpbF][32];

  const int t = threadIdx.x;
  {
    const float4* src = (const float4*)w1;
    float4* dst = (float4*)&sW1[0][0];
#pragma unroll
    for (int i = 0; i < 16; ++i) dst[i * kTpbF + t] = src[i * kTpbF + t];
  }
  __syncthreads();

  const int lane   = t & 63;
  const int wlocal = t >> 6;
  const int wid    = blockIdx.x * kWpbF + wlocal;
  const int myj    = lane >> 1;
  const int j2     = lane & 31;

  const float b1r  = b1[myj];
  const float b2r  = b2[j2];
  const float wor  = wo[j2];
  const float outb = bo[0];
  float w2r[32];
#pragma unroll
  for (int k = 0; k < 32; ++k) w2r[k] = w2[j2 * 32 + k];

  for (int e = 0; e < kElemsF; ++e) {
    const int b = wid * kElemsF + e;
    const int* ip = (lane < kBag) ? (idx_us + (size_t)b * kBag + lane)
                                  : (idx_th + (size_t)b * kBag + (lane - kBag));
    const int vidx = *ip;

    float4 au = make_float4(0.f, 0.f, 0.f, 0.f);
    float4 at = make_float4(0.f, 0.f, 0.f, 0.f);
#pragma unroll
    for (int i = 0; i < kBag; ++i) {
      const int iu = __builtin_amdgcn_readlane(vidx, i);
      const float4 v = ((const float4*)(emb + (size_t)iu * kHidden))[lane];
      au.x += v.x; au.y += v.y; au.z += v.z; au.w += v.w;
    }
#pragma unroll
    for (int i = 0; i < kBag; ++i) {
      const int it2 = __builtin_amdgcn_readlane(vidx, i + kBag);
      const float4 v = ((const float4*)(emb + (size_t)it2 * kHidden))[lane];
      at.x += v.x; at.y += v.y; at.z += v.z; at.w += v.w;
    }

    au.x = clip1(au.x); au.y = clip1(au.y); au.z = clip1(au.z); au.w = clip1(au.w);
    at.x = clip1(at.x); at.y = clip1(at.y); at.z = clip1(at.z); at.w = clip1(at.w);

    float p[32];
#pragma unroll
    for (int j = 0; j < 32; ++j) {
      const float4 a = *(const float4*)&sW1[j][4 * lane];
      const float4 c = *(const float4*)&sW1[j][kHidden + 4 * lane];
      p[j] = au.x * a.x + au.y * a.y + au.z * a.z + au.w * a.w +
             at.x * c.x + at.y * c.y + at.z * c.z + at.w * c.w;
    }
    const float y1 = clip1(reduce32(p, lane) + b1r);

    if ((lane & 1) == 0) sY1[wlocal][myj] = y1;
    asm volatile("s_waitcnt lgkmcnt(0)" ::: "memory");

    const float4* y4 = (const float4*)&sY1[wlocal][0];
    float y2 = b2r;
#pragma unroll
    for (int k4 = 0; k4 < 8; ++k4) {
      const float4 y = y4[k4];
      y2 += w2r[4 * k4 + 0] * y.x + w2r[4 * k4 + 1] * y.y +
            w2r[4 * k4 + 2] * y.z + w2r[4 * k4 + 3] * y.w;
    }
    y2 = clip1(y2);

    float acc = y2 * wor;
#pragma unroll
    for (int d = 1; d < 32; d <<= 1) acc += __shfl_xor(acc, d, 64);
    if (lane == 0) out[b] = acc + outb;
  }
}

extern "C" void kernel_launch(void* const* d_in, const int* in_sizes, int n_in,
                              void* d_out, int out_size, void* d_ws, size_t ws_size,
                              hipStream_t stream) {
  const int* idx_us  = (const int*)d_in[0];
  const int* idx_th  = (const int*)d_in[1];
  const float* emb   = (const float*)d_in[2];
  const float* w1    = (const float*)d_in[3];
  const float* b1    = (const float*)d_in[4];
  const float* w2    = (const float*)d_in[5];
  const float* b2    = (const float*)d_in[6];
  const float* wo    = (const float*)d_in[7];
  const float* bo    = (const float*)d_in[8];
  float* out         = (float*)d_out;

  const size_t embh_bytes = (size_t)kFeat * kHidden * sizeof(__half);  // 21 MB
  if (ws_size >= embh_bytes) {
    __half* embh = (__half*)d_ws;
    cvt_emb<<<2048, 256, 0, stream>>>((const float4*)emb, (uint2*)embh);
    nnue_fwd_h<<<kBlocksH, kTpb, 0, stream>>>(idx_us, idx_th, embh, w1, b1, w2,
                                              b2, wo, bo, out);
  } else {
    nnue_fwd_f32<<<kBlocksF, kTpbF, 0, stream>>>(idx_us, idx_th, emb, w1, b1,
                                                 w2, b2, wo, bo, out);
  }
}